// Round 2
// baseline (616.179 us; speedup 1.0000x reference)
//
#include <hip/hip_runtime.h>
#include <cstdint>
#include <cstddef>

// ---------------------------------------------------------------------------
// KANAdaptiveFusion: fused = [bases(x) | silu(x)] @ W'^T ; LayerNorm over OUT.
//   B=16384, IN=1024, OUT=512, COEF=8 -> K' = 9216.
// Round 2: T2 XOR swizzle on both LDS tiles (B side via pre-swizzled global
// W' so global_load_lds keeps a linear dest — rule #21), single b128 write
// per spline element, 64x128 tile for 4 blocks/CU occupancy.
// ---------------------------------------------------------------------------

#define BATCH    16384
#define IN_DIM   1024
#define OUT_DIM  512
#define K_SPLINE 8192
#define KTOT     9216
#define BM       64
#define BN       128
#define BK       64
#define NCHUNK        (KTOT / BK)      // 144
#define SPLINE_CHUNKS (K_SPLINE / BK)  // 128

typedef __attribute__((ext_vector_type(8))) short  short8;
typedef __attribute__((ext_vector_type(4))) float  f32x4;

static __device__ __forceinline__ unsigned short f2bf(float f) {
    unsigned int u = __float_as_uint(f);
    unsigned int r = u + 0x7fffu + ((u >> 16) & 1u);
    return (unsigned short)(r >> 16);
}

// ---------------------------------------------------------------------------
// prep: build W' bf16 (OUT_DIM x KTOT row-major) PRE-SWIZZLED: within each
// 64-element K-block, 8-element chunk cl is stored at chunk cl ^ (o&7).
// GEMM stages B linearly (global_load_lds) and XORs on the LDS read.
// ---------------------------------------------------------------------------
__global__ void prep_w_kernel(const float* __restrict__ bw,
                              const float* __restrict__ sw,
                              const float* __restrict__ sc,
                              unsigned short* __restrict__ Wp) {
    int t = blockIdx.x * 256 + threadIdx.x;      // < 512 * 1152
    int o = t / 1152;
    int g = t - o * 1152;
    int sz = o & 7;
    unsigned short o8[8];
    size_t dst;
    if (g < 1024) {                 // spline region: i = g, coefs 0..7
        float s = sc[(size_t)o * 1024 + g];
        const float* w = sw + ((size_t)o * 1024 + g) * 8;
        #pragma unroll
        for (int k = 0; k < 8; ++k) o8[k] = f2bf(w[k] * s);
        // logical k = g*8 .. g*8+7 -> K-block g>>3, chunk g&7
        dst = (size_t)o * KTOT + (size_t)(g >> 3) * 64 + (size_t)(((g & 7) ^ sz)) * 8;
    } else {                        // base region: 8 i's per thread
        int gi = g - 1024;          // 0..127 chunk index in base region
        const float* w = bw + (size_t)o * 1024 + gi * 8;
        #pragma unroll
        for (int k = 0; k < 8; ++k) o8[k] = f2bf(w[k]);
        dst = (size_t)o * KTOT + K_SPLINE + (size_t)(gi >> 3) * 64 + (size_t)(((gi & 7) ^ sz)) * 8;
    }
    *reinterpret_cast<short8*>(Wp + dst) = *reinterpret_cast<const short8*>(o8);
}

// ---------------------------------------------------------------------------
// fused-basis bf16 MFMA GEMM. 64x128 tile, BK=64, 256 threads (4 waves in
// 2x2: each wave 32x64 = 2x4 frags of 16x16x32). Grid (256,4) = 1024 blocks.
// ---------------------------------------------------------------------------
__launch_bounds__(256, 4)
__global__ void kan_gemm_kernel(const float* __restrict__ rgb,
                                const float* __restrict__ tac,
                                const unsigned short* __restrict__ Wp,
                                float* __restrict__ out) {
    __shared__ unsigned short At[BM][BK];   //  8 KB, chunk-swizzled
    __shared__ unsigned short Bt[BN][BK];   // 16 KB, chunk-swizzled (via Wp)

    const int tid  = threadIdx.x;
    const int lane = tid & 63;
    const int wid  = tid >> 6;
    const int b0   = blockIdx.x * BM;
    const int n0   = blockIdx.y * BN;
    const int wm   = (wid & 1) * 32;
    const int wn   = (wid >> 1) * 64;

    f32x4 acc[2][4];
    #pragma unroll
    for (int m = 0; m < 2; ++m)
        #pragma unroll
        for (int n = 0; n < 4; ++n)
            acc[m][n] = (f32x4){0.f, 0.f, 0.f, 0.f};

    for (int kc = 0; kc < NCHUNK; ++kc) {
        // ---------------- stage A (computed on the fly, swizzled) ----------
        if (kc < SPLINE_CHUNKS) {
            // 8 input features per chunk; 512 (row, i) pairs; one b128 store
            // of all 8 basis values per pair (select-built, reg-resident).
            int i0 = kc * 8;
            const float* xs = (i0 < 512) ? rgb : tac;
            int ic = (i0 < 512) ? i0 : (i0 - 512);
            #pragma unroll
            for (int rep = 0; rep < 2; ++rep) {
                int e  = tid + rep * 256;           // 0..511
                int r  = e >> 3;
                int il = e & 7;
                float x = xs[(size_t)(b0 + r) * 512 + ic + il];
                // knots g[t] = -2.2 + 0.4*t ; 11 valid intervals
                float tpos = (x + 2.2f) * 2.5f;
                float fj   = floorf(tpos);
                int   j    = (int)fj;
                bool  inr  = (j >= 0) && (j <= 10);
                float u  = tpos - fj;
                float v  = 1.f - u;
                float u2 = u * u;
                float u3 = u2 * u;
                const float c6 = 1.f / 6.f;
                float n0v = v * v * v * c6;
                float n1v = (3.f * u3 - 6.f * u2 + 4.f) * c6;
                float n2v = (-3.f * u3 + 3.f * u2 + 3.f * u + 1.f) * c6;
                float n3v = u3 * c6;
                unsigned short o8[8];
                #pragma unroll
                for (int k = 0; k < 8; ++k) {
                    int d = k - j + 3;              // 0..3 -> n0..n3
                    float val = (d == 0) ? n0v : (d == 1) ? n1v
                              : (d == 2) ? n2v : (d == 3) ? n3v : 0.f;
                    o8[k] = inr ? f2bf(val) : (unsigned short)0;
                }
                *reinterpret_cast<short8*>(&At[r][(il ^ (r & 7)) * 8]) =
                    *reinterpret_cast<const short8*>(o8);
            }
        } else {
            // base path: 64 features per chunk, A col = silu(x)
            int i0 = (kc - SPLINE_CHUNKS) * 64;
            const float* xs = (i0 < 512) ? rgb : tac;
            int ic = (i0 < 512) ? i0 : (i0 - 512);
            #pragma unroll
            for (int rep = 0; rep < 2; ++rep) {
                int gq = tid + rep * 256;           // 0..511 groups of 8 cols
                int r  = gq >> 3;
                int c8 = gq & 7;
                const float* xp = xs + (size_t)(b0 + r) * 512 + ic + c8 * 8;
                f32x4 x0 = *reinterpret_cast<const f32x4*>(xp);
                f32x4 x1 = *reinterpret_cast<const f32x4*>(xp + 4);
                unsigned short o8[8];
                #pragma unroll
                for (int q = 0; q < 4; ++q) {
                    float a = x0[q];
                    o8[q]     = f2bf(a / (1.f + __expf(-a)));
                    float b = x1[q];
                    o8[q + 4] = f2bf(b / (1.f + __expf(-b)));
                }
                *reinterpret_cast<short8*>(&At[r][(c8 ^ (r & 7)) * 8]) =
                    *reinterpret_cast<const short8*>(o8);
            }
        }

        // ------------- stage B: global_load_lds width=16 (linear dest) -----
        {
            int k0g = kc * BK;
            #pragma unroll
            for (int rp = 0; rp < 4; ++rp) {
                int row0 = rp * 32 + wid * 8;   // wave-uniform LDS base
                const unsigned short* gp =
                    Wp + (size_t)(n0 + row0 + (lane >> 3)) * KTOT + k0g + (lane & 7) * 8;
                __builtin_amdgcn_global_load_lds(
                    (const __attribute__((address_space(1))) unsigned int*)gp,
                    (__attribute__((address_space(3))) unsigned int*)&Bt[row0][0],
                    16, 0, 0);
            }
        }
        asm volatile("s_waitcnt vmcnt(0) lgkmcnt(0)" ::: "memory");
        __syncthreads();

        // ---------------- MFMA: 2 k-substeps of 32 ----------------
        #pragma unroll
        for (int ks = 0; ks < 2; ++ks) {
            int cb = ks * 4 + (lane >> 4);          // logical 16B chunk 0..7
            short8 af[2], bfr[4];
            #pragma unroll
            for (int m = 0; m < 2; ++m) {
                int row = wm + m * 16 + (lane & 15);
                af[m] = *reinterpret_cast<const short8*>(&At[row][(cb ^ (row & 7)) * 8]);
            }
            #pragma unroll
            for (int n = 0; n < 4; ++n) {
                int row = wn + n * 16 + (lane & 15);
                bfr[n] = *reinterpret_cast<const short8*>(&Bt[row][(cb ^ (row & 7)) * 8]);
            }
            #pragma unroll
            for (int m = 0; m < 2; ++m)
                #pragma unroll
                for (int n = 0; n < 4; ++n)
                    acc[m][n] = __builtin_amdgcn_mfma_f32_16x16x32_bf16(
                        af[m], bfr[n], acc[m][n], 0, 0, 0);
        }
        __syncthreads();
    }

    // ---------------- epilogue: store pre-LN fused to d_out ----------------
    #pragma unroll
    for (int m = 0; m < 2; ++m) {
        int row = b0 + wm + m * 16 + ((lane >> 4) << 2);
        #pragma unroll
        for (int n = 0; n < 4; ++n) {
            int col = n0 + wn + n * 16 + (lane & 15);
            #pragma unroll
            for (int jj = 0; jj < 4; ++jj)
                out[(size_t)(row + jj) * OUT_DIM + col] = acc[m][n][jj];
        }
    }
}

// ---------------------------------------------------------------------------
// LayerNorm over OUT=512, in place on d_out. One wave per row.
// ---------------------------------------------------------------------------
__global__ void ln_kernel(float* __restrict__ io,
                          const float* __restrict__ gamma,
                          const float* __restrict__ beta) {
    int row  = blockIdx.x * 4 + (threadIdx.x >> 6);
    int lane = threadIdx.x & 63;
    float* p = io + (size_t)row * OUT_DIM;
    f32x4 v0 = *reinterpret_cast<const f32x4*>(p + lane * 4);
    f32x4 v1 = *reinterpret_cast<const f32x4*>(p + 256 + lane * 4);
    float s  = 0.f, ss = 0.f;
    #pragma unroll
    for (int q = 0; q < 4; ++q) {
        s  += v0[q] + v1[q];
        ss += v0[q] * v0[q] + v1[q] * v1[q];
    }
    #pragma unroll
    for (int off = 1; off < 64; off <<= 1) {
        s  += __shfl_xor(s, off);
        ss += __shfl_xor(ss, off);
    }
    float mu  = s * (1.f / 512.f);
    float var = ss * (1.f / 512.f) - mu * mu;
    float rs  = rsqrtf(var + 1e-5f);
    f32x4 g0 = *reinterpret_cast<const f32x4*>(gamma + lane * 4);
    f32x4 g1 = *reinterpret_cast<const f32x4*>(gamma + 256 + lane * 4);
    f32x4 b0 = *reinterpret_cast<const f32x4*>(beta + lane * 4);
    f32x4 b1 = *reinterpret_cast<const f32x4*>(beta + 256 + lane * 4);
    f32x4 r0, r1;
    #pragma unroll
    for (int q = 0; q < 4; ++q) {
        r0[q] = (v0[q] - mu) * rs * g0[q] + b0[q];
        r1[q] = (v1[q] - mu) * rs * g1[q] + b1[q];
    }
    *reinterpret_cast<f32x4*>(p + lane * 4)       = r0;
    *reinterpret_cast<f32x4*>(p + 256 + lane * 4) = r1;
}

// ---------------------------------------------------------------------------
extern "C" void kernel_launch(void* const* d_in, const int* in_sizes, int n_in,
                              void* d_out, int out_size, void* d_ws, size_t ws_size,
                              hipStream_t stream) {
    const float* rgb   = (const float*)d_in[0];
    const float* tac   = (const float*)d_in[1];
    const float* bw    = (const float*)d_in[2];
    const float* sw    = (const float*)d_in[3];
    const float* sc    = (const float*)d_in[4];
    const float* gamma = (const float*)d_in[5];
    const float* beta  = (const float*)d_in[6];
    float* out = (float*)d_out;
    unsigned short* Wp = (unsigned short*)d_ws;   // 512*9216*2 = 9.4 MB

    prep_w_kernel<<<2304, 256, 0, stream>>>(bw, sw, sc, Wp);

    dim3 g(BATCH / BM, OUT_DIM / BN);             // (256, 4)
    kan_gemm_kernel<<<g, 256, 0, stream>>>(rgb, tac, Wp, out);

    ln_kernel<<<BATCH / 4, 256, 0, stream>>>(out, gamma, beta);
}

// Round 3
// 351.911 us; speedup vs baseline: 1.7510x; 1.7510x over previous
//
#include <hip/hip_runtime.h>
#include <cstdint>
#include <cstddef>

// ---------------------------------------------------------------------------
// KANAdaptiveFusion: fused = [bases(x) | silu(x)] @ W'^T ; LayerNorm over OUT.
// Round 3: BN=512 (basis computed ONCE per x element), split-K=2 for grid
// parallelism (f32 partials in ws, reduce+LN kernel), basis-VALU/MFMA overlap
// via reg-staged A with post-barrier LDS write, B double-buffered gload_lds.
// Swizzle addressing identical to round 2 (measured 0 bank conflicts).
// ---------------------------------------------------------------------------

#define BATCH    16384
#define OUT_DIM  512
#define K_SPLINE 8192
#define KTOT     9216
#define BK       64
#define NCHUNK        (KTOT / BK)      // 144
#define SPLINE_CHUNKS (K_SPLINE / BK)  // 128

typedef __attribute__((ext_vector_type(8))) short  short8;
typedef __attribute__((ext_vector_type(4))) float  f32x4;

static __device__ __forceinline__ unsigned short f2bf(float f) {
    unsigned int u = __float_as_uint(f);
    unsigned int r = u + 0x7fffu + ((u >> 16) & 1u);
    return (unsigned short)(r >> 16);
}

// ---------------------------------------------------------------------------
// prep: build W' bf16 (OUT_DIM x KTOT row-major) PRE-SWIZZLED: within each
// 64-element K-block, 8-element chunk cl stored at chunk cl ^ (o&7).
// ---------------------------------------------------------------------------
__global__ void prep_w_kernel(const float* __restrict__ bw,
                              const float* __restrict__ sw,
                              const float* __restrict__ sc,
                              unsigned short* __restrict__ Wp) {
    int t = blockIdx.x * 256 + threadIdx.x;      // < 512 * 1152
    int o = t / 1152;
    int g = t - o * 1152;
    int sz = o & 7;
    unsigned short o8[8];
    size_t dst;
    if (g < 1024) {                 // spline region: i = g, coefs 0..7
        float s = sc[(size_t)o * 1024 + g];
        const float* w = sw + ((size_t)o * 1024 + g) * 8;
        #pragma unroll
        for (int k = 0; k < 8; ++k) o8[k] = f2bf(w[k] * s);
        dst = (size_t)o * KTOT + (size_t)(g >> 3) * 64 + (size_t)(((g & 7) ^ sz)) * 8;
    } else {                        // base region
        int gi = g - 1024;          // 0..127
        const float* w = bw + (size_t)o * 1024 + gi * 8;
        #pragma unroll
        for (int k = 0; k < 8; ++k) o8[k] = f2bf(w[k]);
        dst = (size_t)o * KTOT + K_SPLINE + (size_t)(gi >> 3) * 64 + (size_t)(((gi & 7) ^ sz)) * 8;
    }
    *reinterpret_cast<short8*>(Wp + dst) = *reinterpret_cast<const short8*>(o8);
}

// ---------------------------------------------------------------------------
// GEMM: BM_ x 512 tile, BK=64, 512 threads (8 waves). A single-buffered
// (reg-staged, written post-barrier), B double-buffered via global_load_lds.
// Each block handles K-chunks [blockIdx.y*cps, +cps), writes f32 to
// dest_base + blockIdx.y * BATCH*OUT_DIM.
// ---------------------------------------------------------------------------
template<int BM_>
__launch_bounds__(512, 2)
__global__ void kan_gemm_kernel(const float* __restrict__ rgb,
                                const float* __restrict__ tac,
                                const unsigned short* __restrict__ Wp,
                                float* __restrict__ dest_base,
                                int cps) {
    constexpr int WAVES_M = BM_ / 64;          // 2 (BM=128) or 1 (BM=64)
    constexpr int WAVES_N = 8 / WAVES_M;       // 4 or 8
    constexpr int WN      = OUT_DIM / WAVES_N; // 128 or 64
    constexpr int NF      = WN / 16;           // 8 or 4
    constexpr int REPS    = (BM_ * 8) / 512;   // 2 or 1

    __shared__ unsigned short At[BM_][BK];         // 16 or 8 KB
    __shared__ unsigned short Bt[2][OUT_DIM][BK];  // 128 KB

    const int tid  = threadIdx.x;
    const int lane = tid & 63;
    const int wid  = tid >> 6;
    const int b0   = blockIdx.x * BM_;
    const int wr   = wid % WAVES_M;
    const int wc   = wid / WAVES_M;
    const int kc0  = blockIdx.y * cps;
    const int kc1  = kc0 + cps;
    float* dest = dest_base + (size_t)blockIdx.y * BATCH * OUT_DIM;

    f32x4 acc[4][NF];
    #pragma unroll
    for (int m = 0; m < 4; ++m)
        #pragma unroll
        for (int n = 0; n < NF; ++n)
            acc[m][n] = (f32x4){0.f, 0.f, 0.f, 0.f};

    short8 sa[REPS];   // staged A values for the next chunk

    auto stage_regs = [&](int kc) {
        if (kc < SPLINE_CHUNKS) {
            int i0 = kc * 8;
            const float* xs = (i0 < 512) ? rgb : tac;
            int ic = (i0 < 512) ? i0 : (i0 - 512);
            #pragma unroll
            for (int rep = 0; rep < REPS; ++rep) {
                int e  = tid + rep * 512;
                int r  = e >> 3;
                int il = e & 7;
                float x = xs[(size_t)(b0 + r) * 512 + ic + il];
                float tpos = (x + 2.2f) * 2.5f;   // knots -2.2 + 0.4*t
                float fj   = floorf(tpos);
                int   j    = (int)fj;
                bool  inr  = (j >= 0) && (j <= 10);
                float u  = tpos - fj;
                float v  = 1.f - u;
                float u2 = u * u;
                float u3 = u2 * u;
                const float c6 = 1.f / 6.f;
                float n0v = v * v * v * c6;
                float n1v = (3.f * u3 - 6.f * u2 + 4.f) * c6;
                float n2v = (-3.f * u3 + 3.f * u2 + 3.f * u + 1.f) * c6;
                float n3v = u3 * c6;
                unsigned short o8[8];
                #pragma unroll
                for (int k = 0; k < 8; ++k) {
                    int d = k - j + 3;
                    float val = (d == 0) ? n0v : (d == 1) ? n1v
                              : (d == 2) ? n2v : (d == 3) ? n3v : 0.f;
                    o8[k] = inr ? f2bf(val) : (unsigned short)0;
                }
                sa[rep] = *reinterpret_cast<const short8*>(o8);
            }
        } else {
            int i0 = (kc - SPLINE_CHUNKS) * 64;
            const float* xs = (i0 < 512) ? rgb : tac;
            int ic = (i0 < 512) ? i0 : (i0 - 512);
            #pragma unroll
            for (int rep = 0; rep < REPS; ++rep) {
                int gq = tid + rep * 512;
                int r  = gq >> 3;
                int c8 = gq & 7;
                const float* xp = xs + (size_t)(b0 + r) * 512 + ic + c8 * 8;
                f32x4 x0 = *reinterpret_cast<const f32x4*>(xp);
                f32x4 x1 = *reinterpret_cast<const f32x4*>(xp + 4);
                unsigned short o8[8];
                #pragma unroll
                for (int q = 0; q < 4; ++q) {
                    float a = x0[q];
                    o8[q]     = f2bf(a / (1.f + __expf(-a)));
                    float b = x1[q];
                    o8[q + 4] = f2bf(b / (1.f + __expf(-b)));
                }
                sa[rep] = *reinterpret_cast<const short8*>(o8);
            }
        }
    };

    auto write_A = [&]() {
        #pragma unroll
        for (int rep = 0; rep < REPS; ++rep) {
            int e = tid + rep * 512;
            int r = e >> 3;
            int c = e & 7;
            *reinterpret_cast<short8*>(&At[r][(c ^ (r & 7)) * 8]) = sa[rep];
        }
    };

    auto gload_B = [&](int kc, int buf) {
        int k0g = kc * BK;
        #pragma unroll
        for (int rp = 0; rp < 8; ++rp) {
            int row0 = wid * 64 + rp * 8;   // wave-uniform LDS base
            const unsigned short* gp =
                Wp + (size_t)(row0 + (lane >> 3)) * KTOT + k0g + (lane & 7) * 8;
            __builtin_amdgcn_global_load_lds(
                (const __attribute__((address_space(1))) unsigned int*)gp,
                (__attribute__((address_space(3))) unsigned int*)&Bt[buf][row0][0],
                16, 0, 0);
        }
    };

    // ---------------- prologue: stage chunk kc0 ----------------
    stage_regs(kc0);
    write_A();
    gload_B(kc0, kc0 & 1);
    asm volatile("s_waitcnt vmcnt(0) lgkmcnt(0)" ::: "memory");
    __syncthreads();

    // ---------------- main loop ----------------
    for (int t = kc0; t < kc1; ++t) {
        const bool more = (t + 1 < kc1);
        if (more) {
            gload_B(t + 1, (t + 1) & 1);  // async into other B buffer
            stage_regs(t + 1);            // VALU, interleaves with MFMA below
        }
        // MFMA on chunk t
        #pragma unroll
        for (int ks = 0; ks < 2; ++ks) {
            int cb = ks * 4 + (lane >> 4);
            short8 af[4];
            #pragma unroll
            for (int m = 0; m < 4; ++m) {
                int row = wr * 64 + m * 16 + (lane & 15);
                af[m] = *reinterpret_cast<const short8*>(&At[row][(cb ^ (row & 7)) * 8]);
            }
            #pragma unroll
            for (int n = 0; n < NF; ++n) {
                int row = wc * WN + n * 16 + (lane & 15);
                short8 bf = *reinterpret_cast<const short8*>(
                    &Bt[t & 1][row][(cb ^ (row & 7)) * 8]);
                #pragma unroll
                for (int m = 0; m < 4; ++m)
                    acc[m][n] = __builtin_amdgcn_mfma_f32_16x16x32_bf16(
                        af[m], bf, acc[m][n], 0, 0, 0);
            }
        }
        __syncthreads();                  // all waves done reading At
        if (more) write_A();              // overwrite A tile for chunk t+1
        asm volatile("s_waitcnt vmcnt(0) lgkmcnt(0)" ::: "memory");
        __syncthreads();
    }

    // ---------------- epilogue: f32 store ----------------
    #pragma unroll
    for (int m = 0; m < 4; ++m) {
        int row = b0 + wr * 64 + m * 16 + ((lane >> 4) << 2);
        #pragma unroll
        for (int n = 0; n < NF; ++n) {
            int col = wc * WN + n * 16 + (lane & 15);
            #pragma unroll
            for (int jj = 0; jj < 4; ++jj)
                dest[(size_t)(row + jj) * OUT_DIM + col] = acc[m][n][jj];
        }
    }
}

// ---------------------------------------------------------------------------
// reduce partials + LayerNorm: out = LN(P0 + P1). One wave per row.
// ---------------------------------------------------------------------------
__global__ void reduce_ln_kernel(const float* __restrict__ P0,
                                 const float* __restrict__ P1,
                                 const float* __restrict__ gamma,
                                 const float* __restrict__ beta,
                                 float* __restrict__ out) {
    int row  = blockIdx.x * 4 + (threadIdx.x >> 6);
    int lane = threadIdx.x & 63;
    const float* p0 = P0 + (size_t)row * OUT_DIM;
    const float* p1 = P1 + (size_t)row * OUT_DIM;
    f32x4 a0 = *reinterpret_cast<const f32x4*>(p0 + lane * 4);
    f32x4 a1 = *reinterpret_cast<const f32x4*>(p0 + 256 + lane * 4);
    f32x4 b0 = *reinterpret_cast<const f32x4*>(p1 + lane * 4);
    f32x4 b1 = *reinterpret_cast<const f32x4*>(p1 + 256 + lane * 4);
    f32x4 v0, v1;
    #pragma unroll
    for (int q = 0; q < 4; ++q) { v0[q] = a0[q] + b0[q]; v1[q] = a1[q] + b1[q]; }
    float s = 0.f, ss = 0.f;
    #pragma unroll
    for (int q = 0; q < 4; ++q) {
        s  += v0[q] + v1[q];
        ss += v0[q] * v0[q] + v1[q] * v1[q];
    }
    #pragma unroll
    for (int off = 1; off < 64; off <<= 1) {
        s  += __shfl_xor(s, off);
        ss += __shfl_xor(ss, off);
    }
    float mu  = s * (1.f / 512.f);
    float var = ss * (1.f / 512.f) - mu * mu;
    float rs  = rsqrtf(var + 1e-5f);
    f32x4 g0 = *reinterpret_cast<const f32x4*>(gamma + lane * 4);
    f32x4 g1 = *reinterpret_cast<const f32x4*>(gamma + 256 + lane * 4);
    f32x4 e0 = *reinterpret_cast<const f32x4*>(beta + lane * 4);
    f32x4 e1 = *reinterpret_cast<const f32x4*>(beta + 256 + lane * 4);
    float* po = out + (size_t)row * OUT_DIM;
    f32x4 r0, r1;
    #pragma unroll
    for (int q = 0; q < 4; ++q) {
        r0[q] = (v0[q] - mu) * rs * g0[q] + e0[q];
        r1[q] = (v1[q] - mu) * rs * g1[q] + e1[q];
    }
    *reinterpret_cast<f32x4*>(po + lane * 4)       = r0;
    *reinterpret_cast<f32x4*>(po + 256 + lane * 4) = r1;
}

// ---------------------------------------------------------------------------
// LayerNorm in place (fallback path, no split).
// ---------------------------------------------------------------------------
__global__ void ln_kernel(float* __restrict__ io,
                          const float* __restrict__ gamma,
                          const float* __restrict__ beta) {
    int row  = blockIdx.x * 4 + (threadIdx.x >> 6);
    int lane = threadIdx.x & 63;
    float* p = io + (size_t)row * OUT_DIM;
    f32x4 v0 = *reinterpret_cast<const f32x4*>(p + lane * 4);
    f32x4 v1 = *reinterpret_cast<const f32x4*>(p + 256 + lane * 4);
    float s = 0.f, ss = 0.f;
    #pragma unroll
    for (int q = 0; q < 4; ++q) {
        s  += v0[q] + v1[q];
        ss += v0[q] * v0[q] + v1[q] * v1[q];
    }
    #pragma unroll
    for (int off = 1; off < 64; off <<= 1) {
        s  += __shfl_xor(s, off);
        ss += __shfl_xor(ss, off);
    }
    float mu  = s * (1.f / 512.f);
    float var = ss * (1.f / 512.f) - mu * mu;
    float rs  = rsqrtf(var + 1e-5f);
    f32x4 g0 = *reinterpret_cast<const f32x4*>(gamma + lane * 4);
    f32x4 g1 = *reinterpret_cast<const f32x4*>(gamma + 256 + lane * 4);
    f32x4 e0 = *reinterpret_cast<const f32x4*>(beta + lane * 4);
    f32x4 e1 = *reinterpret_cast<const f32x4*>(beta + 256 + lane * 4);
    f32x4 r0, r1;
    #pragma unroll
    for (int q = 0; q < 4; ++q) {
        r0[q] = (v0[q] - mu) * rs * g0[q] + e0[q];
        r1[q] = (v1[q] - mu) * rs * g1[q] + e1[q];
    }
    *reinterpret_cast<f32x4*>(p + lane * 4)       = r0;
    *reinterpret_cast<f32x4*>(p + 256 + lane * 4) = r1;
}

// ---------------------------------------------------------------------------
extern "C" void kernel_launch(void* const* d_in, const int* in_sizes, int n_in,
                              void* d_out, int out_size, void* d_ws, size_t ws_size,
                              hipStream_t stream) {
    const float* rgb   = (const float*)d_in[0];
    const float* tac   = (const float*)d_in[1];
    const float* bw    = (const float*)d_in[2];
    const float* sw    = (const float*)d_in[3];
    const float* sc    = (const float*)d_in[4];
    const float* gamma = (const float*)d_in[5];
    const float* beta  = (const float*)d_in[6];
    float* out = (float*)d_out;
    unsigned short* Wp = (unsigned short*)d_ws;        // 9.4 MB at ws[0]

    prep_w_kernel<<<2304, 256, 0, stream>>>(bw, sw, sc, Wp);

    const size_t PART  = (size_t)BATCH * OUT_DIM * sizeof(float);  // 32 MB
    const size_t POFF  = 16ull << 20;                              // 16 MB
    if (ws_size >= POFF + 2 * PART) {
        // split-K=2: BM=128, grid (128, 2) = 256 blocks, partials in ws
        float* P = (float*)((char*)d_ws + POFF);
        dim3 g(BATCH / 128, 2);
        kan_gemm_kernel<128><<<g, 512, 0, stream>>>(rgb, tac, Wp, P, NCHUNK / 2);
        reduce_ln_kernel<<<BATCH / 4, 256, 0, stream>>>(
            P, P + (size_t)BATCH * OUT_DIM, gamma, beta, out);
    } else {
        // fallback: BM=64, full K, write to out, LN in place
        dim3 g(BATCH / 64, 1);
        kan_gemm_kernel<64><<<g, 512, 0, stream>>>(rgb, tac, Wp, out, NCHUNK);
        ln_kernel<<<BATCH / 4, 256, 0, stream>>>(out, gamma, beta);
    }
}